// Round 31
// baseline (34.578 us; speedup 1.0000x reference)
//
#include <hip/hip_runtime.h>
#include <cstdint>
#include <cstddef>

#define NCOL 12288    // N
#define KHALF 2048    // K/2 packed rows; K=4096, 32 groups of 64 kh-rows
#define NGRP 32
#define NCHUNK 256    // K-split factor
#define CH 8          // kh-rows per chunk (chunk lies inside one dequant group)

// round-to-nearest-even f32 -> bf16 value, returned as f32 (low mantissa cleared)
__device__ __forceinline__ float bf16_rne(float f) {
    uint32_t u; __builtin_memcpy(&u, &f, 4);
    u = (u + 0x7FFFu + ((u >> 16) & 1u)) & 0xFFFF0000u;
    float r; __builtin_memcpy(&r, &u, 4);
    return r;
}

// ---------------------------------------------------------------------------
// K-split partial GEMV. x/scales/zeros are f32 (bf16-valued); w_q int32.
// Block: 256 threads x 4 consecutive cols (uint4 16B loads) = 1024 cols.
// Grid: (NCOL/1024, NCHUNK) = (12, 256) = 3072 blocks -> 12 blocks/CU.
// x values are wave-uniform -> compiler emits scalar loads; no LDS/barrier.
// ---------------------------------------------------------------------------
__global__ __launch_bounds__(256) void gemv_part(
    const float* __restrict__ x,       // f32[4096]
    const uint32_t* __restrict__ wq,   // [KHALF][NCOL]
    const float* __restrict__ sc,      // [32][NCOL]
    const float* __restrict__ zr,      // [32][NCOL]
    float* __restrict__ ws)            // [NCHUNK][NCOL]
{
    const int tx = threadIdx.x;
    const int chunk = blockIdx.y;
    const int kh0 = chunk * CH;
    const int g = kh0 >> 6;            // dequant group (CH=8 divides 64)

    const int n0 = blockIdx.x * 1024 + tx * 4;
    const float4 s4 = *(const float4*)(sc + (size_t)g * NCOL + n0);
    const float4 z4 = *(const float4*)(zr + (size_t)g * NCOL + n0);

    float a0 = 0.f, a1 = 0.f, a2 = 0.f, a3 = 0.f;
    const uint4* wp = (const uint4*)(wq + (size_t)kh0 * NCOL + n0);

    #pragma unroll
    for (int r = 0; r < CH; ++r) {
        const uint4 v = wp[(size_t)r * (NCOL / 4)];
        const float xl = x[2 * (kh0 + r)];      // uniform -> scalar load
        const float xh = x[2 * (kh0 + r) + 1];
        a0 = fmaf(xl, bf16_rne(((float)(v.x & 15u)        - z4.x) * s4.x), a0);
        a0 = fmaf(xh, bf16_rne(((float)((v.x >> 4) & 15u) - z4.x) * s4.x), a0);
        a1 = fmaf(xl, bf16_rne(((float)(v.y & 15u)        - z4.y) * s4.y), a1);
        a1 = fmaf(xh, bf16_rne(((float)((v.y >> 4) & 15u) - z4.y) * s4.y), a1);
        a2 = fmaf(xl, bf16_rne(((float)(v.z & 15u)        - z4.z) * s4.z), a2);
        a2 = fmaf(xh, bf16_rne(((float)((v.z >> 4) & 15u) - z4.z) * s4.z), a2);
        a3 = fmaf(xl, bf16_rne(((float)(v.w & 15u)        - z4.w) * s4.w), a3);
        a3 = fmaf(xh, bf16_rne(((float)((v.w >> 4) & 15u) - z4.w) * s4.w), a3);
    }

    *(float4*)(ws + (size_t)chunk * NCOL + n0) = make_float4(a0, a1, a2, a3);
}

// Sum the NCHUNK partials; final bf16 rounding; store as FLOAT32 (output dtype).
__global__ __launch_bounds__(256) void reduce_ws(
    const float* __restrict__ ws, float* __restrict__ out)
{
    const int n = blockIdx.x * 256 + threadIdx.x;   // 48 blocks exactly
    float s = 0.f;
    #pragma unroll 16
    for (int j = 0; j < NCHUNK; ++j) s += ws[(size_t)j * NCOL + n];
    out[n] = bf16_rne(s);
}

// Fallback (ws too small): 1 thread per column, full K. Correct, slower.
__global__ void gemv_simple(
    const float* __restrict__ x, const uint32_t* __restrict__ wq,
    const float* __restrict__ sc, const float* __restrict__ zr,
    float* __restrict__ out)
{
    const int n = blockIdx.x * blockDim.x + threadIdx.x;
    if (n >= NCOL) return;
    float acc = 0.f;
    for (int g = 0; g < NGRP; ++g) {
        const float s = sc[(size_t)g * NCOL + n];
        const float z = zr[(size_t)g * NCOL + n];
        #pragma unroll 8
        for (int r = 0; r < 64; ++r) {
            const int kh = g * 64 + r;
            const uint32_t e = wq[(size_t)kh * NCOL + n];
            acc = fmaf(x[2 * kh],     bf16_rne(((float)(e & 15u)        - z) * s), acc);
            acc = fmaf(x[2 * kh + 1], bf16_rne(((float)((e >> 4) & 15u) - z) * s), acc);
        }
    }
    out[n] = bf16_rne(acc);
}

extern "C" void kernel_launch(void* const* d_in, const int* in_sizes, int n_in,
                              void* d_out, int out_size, void* d_ws, size_t ws_size,
                              hipStream_t stream) {
    (void)in_sizes; (void)n_in; (void)out_size;
    const float*    x  = (const float*)d_in[0];   // f32 upcast of bf16
    const uint32_t* wq = (const uint32_t*)d_in[1];
    const float*    sc = (const float*)d_in[2];
    const float*    zr = (const float*)d_in[3];
    float* out = (float*)d_out;                   // output dtype is FLOAT32
    float* ws  = (float*)d_ws;

    if (ws_size >= (size_t)NCHUNK * NCOL * 4) {
        gemv_part<<<dim3(NCOL / 1024, NCHUNK), dim3(256), 0, stream>>>(x, wq, sc, zr, ws);
        reduce_ws<<<dim3(NCOL / 256), dim3(256), 0, stream>>>(ws, out);
    } else {
        gemv_simple<<<dim3(NCOL / 64), dim3(64), 0, stream>>>(x, wq, sc, zr, out);
    }
}

// Round 32
// 25.450 us; speedup vs baseline: 1.3587x; 1.3587x over previous
//
#include <hip/hip_runtime.h>
#include <cstdint>
#include <cstddef>

#define NCOL 12288    // N
#define KHALF 2048    // K/2 packed rows; K=4096, 32 groups of 64 kh-rows
#define NGRP 32
#define COLT 256      // columns per block

// round-to-nearest-even f32 -> bf16 value, returned as f32 (low mantissa cleared)
__device__ __forceinline__ float bf16_rne(float f) {
    uint32_t u; __builtin_memcpy(&u, &f, 4);
    u = (u + 0x7FFFu + ((u >> 16) & 1u)) & 0xFFFF0000u;
    float r; __builtin_memcpy(&r, &u, 4);
    return r;
}

// ---------------------------------------------------------------------------
// Block = 256 threads = 4 waves. Covers COLT=256 cols x one full dequant
// group (64 kh-rows); wave w owns rows [16w,16w+16). 4-way LDS reduce, then
// wave 0 writes the group-partial to ws[g][n]. Grid (48, 32) = 1536 blocks.
// Scales/zeros are read exactly ONCE per group. x loads are wave-uniform.
// ---------------------------------------------------------------------------
__global__ __launch_bounds__(256) void gemv_part(
    const float* __restrict__ x,       // f32[4096]
    const uint32_t* __restrict__ wq,   // [KHALF][NCOL]
    const float* __restrict__ sc,      // [32][NCOL]
    const float* __restrict__ zr,      // [32][NCOL]
    float* __restrict__ ws)            // [NGRP][NCOL]
{
    const int tx   = threadIdx.x;
    const int lane = tx & 63;
    const int wave = tx >> 6;                    // 0..3
    const int g    = blockIdx.y;                 // dequant group
    const int kh0  = g * 64 + wave * 16;
    const int n0   = blockIdx.x * COLT + lane * 4;

    const float4 s4 = *(const float4*)(sc + (size_t)g * NCOL + n0);
    const float4 z4 = *(const float4*)(zr + (size_t)g * NCOL + n0);

    float a0 = 0.f, a1 = 0.f, a2 = 0.f, a3 = 0.f;
    const uint4* wp = (const uint4*)(wq + (size_t)kh0 * NCOL + n0);

    #pragma unroll
    for (int r = 0; r < 16; ++r) {
        const uint4 v = wp[(size_t)r * (NCOL / 4)];
        const float xl = x[2 * (kh0 + r)];       // uniform -> scalar load
        const float xh = x[2 * (kh0 + r) + 1];
        a0 = fmaf(xl, bf16_rne(((float)(v.x & 15u)        - z4.x) * s4.x), a0);
        a0 = fmaf(xh, bf16_rne(((float)((v.x >> 4) & 15u) - z4.x) * s4.x), a0);
        a1 = fmaf(xl, bf16_rne(((float)(v.y & 15u)        - z4.y) * s4.y), a1);
        a1 = fmaf(xh, bf16_rne(((float)((v.y >> 4) & 15u) - z4.y) * s4.y), a1);
        a2 = fmaf(xl, bf16_rne(((float)(v.z & 15u)        - z4.z) * s4.z), a2);
        a2 = fmaf(xh, bf16_rne(((float)((v.z >> 4) & 15u) - z4.z) * s4.z), a2);
        a3 = fmaf(xl, bf16_rne(((float)(v.w & 15u)        - z4.w) * s4.w), a3);
        a3 = fmaf(xh, bf16_rne(((float)((v.w >> 4) & 15u) - z4.w) * s4.w), a3);
    }

    __shared__ float red[4][COLT];               // 4 KB
    red[wave][lane * 4 + 0] = a0;
    red[wave][lane * 4 + 1] = a1;
    red[wave][lane * 4 + 2] = a2;
    red[wave][lane * 4 + 3] = a3;
    __syncthreads();

    if (wave == 0) {
        const int c = lane * 4;
        float4 s;
        s.x = (red[0][c + 0] + red[1][c + 0]) + (red[2][c + 0] + red[3][c + 0]);
        s.y = (red[0][c + 1] + red[1][c + 1]) + (red[2][c + 1] + red[3][c + 1]);
        s.z = (red[0][c + 2] + red[1][c + 2]) + (red[2][c + 2] + red[3][c + 2]);
        s.w = (red[0][c + 3] + red[1][c + 3]) + (red[2][c + 3] + red[3][c + 3]);
        *(float4*)(ws + (size_t)g * NCOL + n0) = s;
    }
}

// Sum the 32 group-partials; final bf16 rounding; store as FLOAT32.
__global__ __launch_bounds__(256) void reduce_ws(
    const float* __restrict__ ws, float* __restrict__ out)
{
    const int n = blockIdx.x * 256 + threadIdx.x;   // 48 blocks exactly
    float s = 0.f;
    #pragma unroll
    for (int j = 0; j < NGRP; ++j) s += ws[(size_t)j * NCOL + n];
    out[n] = bf16_rne(s);
}

// Fallback (ws too small): 1 thread per column, full K. Correct, slower.
__global__ void gemv_simple(
    const float* __restrict__ x, const uint32_t* __restrict__ wq,
    const float* __restrict__ sc, const float* __restrict__ zr,
    float* __restrict__ out)
{
    const int n = blockIdx.x * blockDim.x + threadIdx.x;
    if (n >= NCOL) return;
    float acc = 0.f;
    for (int g = 0; g < NGRP; ++g) {
        const float s = sc[(size_t)g * NCOL + n];
        const float z = zr[(size_t)g * NCOL + n];
        #pragma unroll 8
        for (int r = 0; r < 64; ++r) {
            const int kh = g * 64 + r;
            const uint32_t e = wq[(size_t)kh * NCOL + n];
            acc = fmaf(x[2 * kh],     bf16_rne(((float)(e & 15u)        - z) * s), acc);
            acc = fmaf(x[2 * kh + 1], bf16_rne(((float)((e >> 4) & 15u) - z) * s), acc);
        }
    }
    out[n] = bf16_rne(acc);
}

extern "C" void kernel_launch(void* const* d_in, const int* in_sizes, int n_in,
                              void* d_out, int out_size, void* d_ws, size_t ws_size,
                              hipStream_t stream) {
    (void)in_sizes; (void)n_in; (void)out_size;
    const float*    x  = (const float*)d_in[0];   // f32 upcast of bf16
    const uint32_t* wq = (const uint32_t*)d_in[1];
    const float*    sc = (const float*)d_in[2];
    const float*    zr = (const float*)d_in[3];
    float* out = (float*)d_out;                   // output dtype is FLOAT32
    float* ws  = (float*)d_ws;

    if (ws_size >= (size_t)NGRP * NCOL * 4) {
        gemv_part<<<dim3(NCOL / COLT, NGRP), dim3(256), 0, stream>>>(x, wq, sc, zr, ws);
        reduce_ws<<<dim3(NCOL / 256), dim3(256), 0, stream>>>(ws, out);
    } else {
        gemv_simple<<<dim3(NCOL / 64), dim3(64), 0, stream>>>(x, wq, sc, zr, out);
    }
}